// Round 1
// baseline (2568.493 us; speedup 1.0000x reference)
//
#include <hip/hip_runtime.h>
#include <hip/hip_bf16.h>
#include <math.h>

// Problem constants
#define Bc 2
#define Sc 1024
#define Hc 1024
#define NHc 16
#define NKVc 4
#define HDc 64
#define Ec 8
#define TOPKc 2
#define Ic 3584
#define Tc (Bc*Sc)          // 2048 tokens
#define EPSc 1e-5f

// ---------------- ws layout (float units) ----------------
// xn1 / attn share (xn1 dead after qkv). q / xn2 share (q dead after attn).
static const size_t OFF_XN1  = 0;                                    // T*H  (also attn later)
static const size_t OFF_Q    = OFF_XN1 + (size_t)Tc*Hc;              // T*NH*HD (also xn2 later)
static const size_t OFF_K    = OFF_Q   + (size_t)Tc*NHc*HDc;         // T*NKV*HD
static const size_t OFF_V    = OFF_K   + (size_t)Tc*NKVc*HDc;        // T*NKV*HD
static const size_t OFF_ATT  = OFF_V   + (size_t)Tc*NKVc*HDc;        // T*H
static const size_t OFF_XN2  = OFF_ATT + (size_t)Tc*Hc;              // T*H
static const size_t OFF_ACT  = OFF_XN2 + (size_t)Tc*Hc;              // T*TOPK*I
static const size_t OFF_ROUTE= OFF_ACT + (size_t)Tc*TOPKc*Ic;        // int region
// route ints: [0..7]=counts, [8..15]=fill, [16..23]=offsets,
// [24..24+2T)=topk_e, then 2T floats topk_w, 2T ints list_tok, 2T floats list_w

// ---------------- rmsnorm ----------------
__global__ __launch_bounds__(256) void rmsnorm_kernel(const float* __restrict__ x,
                                                      const float* __restrict__ w,
                                                      float* __restrict__ out) {
    int t = blockIdx.x;
    int tid = threadIdx.x;
    const float* row = x + (size_t)t * Hc;
    float ss = 0.f;
    for (int h = tid; h < Hc; h += 256) { float v = row[h]; ss += v*v; }
    __shared__ float red[256];
    red[tid] = ss; __syncthreads();
    for (int s = 128; s > 0; s >>= 1) { if (tid < s) red[tid] += red[tid+s]; __syncthreads(); }
    float scale = rsqrtf(red[0] / (float)Hc + EPSc);
    for (int h = tid; h < Hc; h += 256) out[(size_t)t*Hc + h] = row[h] * scale * w[h];
}

// ---------------- fused QKV GEMM: [2048,1024] @ [1024,1536] ----------------
__global__ __launch_bounds__(256) void qkv_gemm(const float* __restrict__ A,
        const float* __restrict__ wq, const float* __restrict__ wk, const float* __restrict__ wv,
        float* __restrict__ qout, float* __restrict__ kout, float* __restrict__ vout) {
    __shared__ float As[64][17];
    __shared__ float Bs[16][65];
    int n0 = blockIdx.x * 64;   // N = 1536
    int m0 = blockIdx.y * 64;   // M = 2048
    int tid = threadIdx.x;
    int tx = tid & 15, ty = tid >> 4;
    const float* Bp; int ldb, c0;
    if (n0 < 1024)      { Bp = wq; ldb = 1024; c0 = n0; }
    else if (n0 < 1280) { Bp = wk; ldb = 256;  c0 = n0 - 1024; }
    else                { Bp = wv; ldb = 256;  c0 = n0 - 1280; }
    float acc[4][4] = {};
    for (int k0 = 0; k0 < 1024; k0 += 16) {
        #pragma unroll
        for (int i = 0; i < 4; i++) {
            int lin = tid + i*256; int r = lin >> 4, k = lin & 15;
            As[r][k] = A[(size_t)(m0 + r)*Hc + k0 + k];
        }
        #pragma unroll
        for (int i = 0; i < 4; i++) {
            int lin = tid + i*256; int r = lin >> 6, c = lin & 63;
            Bs[r][c] = Bp[(size_t)(k0 + r)*ldb + c0 + c];
        }
        __syncthreads();
        #pragma unroll
        for (int kk = 0; kk < 16; kk++) {
            float a[4], b[4];
            #pragma unroll
            for (int i = 0; i < 4; i++) a[i] = As[ty*4+i][kk];
            #pragma unroll
            for (int j = 0; j < 4; j++) b[j] = Bs[kk][tx*4+j];
            #pragma unroll
            for (int i = 0; i < 4; i++)
                #pragma unroll
                for (int j = 0; j < 4; j++) acc[i][j] += a[i]*b[j];
        }
        __syncthreads();
    }
    #pragma unroll
    for (int i = 0; i < 4; i++) {
        int m = m0 + ty*4 + i;
        #pragma unroll
        for (int j = 0; j < 4; j++) {
            int n = n0 + tx*4 + j;
            float val = acc[i][j];
            if (n < 1024)      qout[(size_t)m*1024 + n] = val;
            else if (n < 1280) kout[(size_t)m*256 + (n-1024)] = val;
            else               vout[(size_t)m*256 + (n-1280)] = val;
        }
    }
}

// ---------------- RoPE (in place on q and k) ----------------
__global__ __launch_bounds__(256) void rope_kernel(float* __restrict__ q, float* __restrict__ k) {
    int idx = blockIdx.x*256 + threadIdx.x;
    const int total = Tc*(NHc+NKVc)*32;
    if (idx >= total) return;
    int d = idx & 31;
    int rest = idx >> 5;
    int head = rest % (NHc+NKVc);
    int t = rest / (NHc+NKVc);
    int s = t & (Sc-1);                 // position = sequence index
    float inv = powf(1.0e6f, -(float)d / 32.0f);
    float ang = (float)s * inv;
    float c = cosf(ang), sn = sinf(ang);
    float* base;
    if (head < NHc) base = q + (size_t)t*1024 + head*64;
    else            base = k + (size_t)t*256  + (head-NHc)*64;
    float x1 = base[d], x2 = base[d+32];
    base[d]    = x1*c - x2*sn;
    base[d+32] = x2*c + x1*sn;
}

// ---------------- flash-style causal attention ----------------
__global__ __launch_bounds__(256) void attn_kernel(const float* __restrict__ q,
        const float* __restrict__ kbuf, const float* __restrict__ vbuf,
        float* __restrict__ attn) {
    __shared__ float Qs[64][65];
    __shared__ float KVs[64][65];   // K tile, then reused for V tile
    __shared__ float Ps[64][65];
    __shared__ float m_s[64], l_s[64], al_s[64];
    int q0 = blockIdx.x * 64;
    int h  = blockIdx.y;
    int b  = blockIdx.z;
    int hk = h >> 2;
    int tid = threadIdx.x;
    int tx = tid & 15, ty = tid >> 4;
    #pragma unroll
    for (int i = 0; i < 16; i++) {
        int lin = tid + i*256; int r = lin >> 6, d = lin & 63;
        Qs[r][d] = q[((size_t)(b*Sc + q0 + r))*1024 + h*64 + d];
    }
    if (tid < 64) { m_s[tid] = -INFINITY; l_s[tid] = 0.f; }
    float O[4][4] = {};
    for (int j0 = 0; j0 <= q0; j0 += 64) {
        __syncthreads();   // protect Ps/KVs from previous iteration
        #pragma unroll
        for (int i = 0; i < 16; i++) {
            int lin = tid + i*256; int r = lin >> 6, d = lin & 63;
            KVs[r][d] = kbuf[((size_t)(b*Sc + j0 + r))*256 + hk*64 + d];
        }
        __syncthreads();
        float sc[4][4] = {};
        for (int d = 0; d < 64; d++) {
            float a[4], bb[4];
            #pragma unroll
            for (int i = 0; i < 4; i++) a[i] = Qs[ty*4+i][d];
            #pragma unroll
            for (int j = 0; j < 4; j++) bb[j] = KVs[tx*4+j][d];
            #pragma unroll
            for (int i = 0; i < 4; i++)
                #pragma unroll
                for (int j = 0; j < 4; j++) sc[i][j] += a[i]*bb[j];
        }
        bool diag = (j0 == q0);
        #pragma unroll
        for (int i = 0; i < 4; i++) {
            int r = ty*4+i;
            #pragma unroll
            for (int j = 0; j < 4; j++) {
                int c = tx*4+j;
                float v = sc[i][j]*0.125f;
                if (diag && c > r) v = -1e30f;
                Ps[r][c] = v;
            }
        }
        __syncthreads();
        // softmax update (64 threads) + V load (all threads)
        if (tid < 64) {
            int r = tid;
            float mx = -1e30f;
            for (int c = 0; c < 64; c++) mx = fmaxf(mx, Ps[r][c]);
            float newm = fmaxf(m_s[r], mx);
            float alpha = expf(m_s[r] - newm);
            float sum = 0.f;
            for (int c = 0; c < 64; c++) { float p = expf(Ps[r][c] - newm); Ps[r][c] = p; sum += p; }
            l_s[r] = l_s[r]*alpha + sum;
            m_s[r] = newm;
            al_s[r] = alpha;
        }
        #pragma unroll
        for (int i = 0; i < 16; i++) {
            int lin = tid + i*256; int r = lin >> 6, d = lin & 63;
            KVs[r][d] = vbuf[((size_t)(b*Sc + j0 + r))*256 + hk*64 + d];
        }
        __syncthreads();
        #pragma unroll
        for (int i = 0; i < 4; i++) {
            float al = al_s[ty*4+i];
            #pragma unroll
            for (int j = 0; j < 4; j++) O[i][j] *= al;
        }
        for (int c = 0; c < 64; c++) {
            float p[4], vv[4];
            #pragma unroll
            for (int i = 0; i < 4; i++) p[i] = Ps[ty*4+i][c];
            #pragma unroll
            for (int j = 0; j < 4; j++) vv[j] = KVs[c][tx*4+j];
            #pragma unroll
            for (int i = 0; i < 4; i++)
                #pragma unroll
                for (int j = 0; j < 4; j++) O[i][j] += p[i]*vv[j];
        }
    }
    #pragma unroll
    for (int i = 0; i < 4; i++) {
        int r = ty*4+i;
        float inv_l = 1.f / l_s[r];
        int m = b*Sc + q0 + r;
        #pragma unroll
        for (int j = 0; j < 4; j++) {
            int d = tx*4+j;
            attn[(size_t)m*1024 + h*64 + d] = O[i][j]*inv_l;
        }
    }
}

// ---------------- WO GEMM + residual: out = resid + attn @ wo ----------------
__global__ __launch_bounds__(256) void wo_gemm(const float* __restrict__ A,
        const float* __restrict__ wo, const float* __restrict__ resid,
        float* __restrict__ out) {
    __shared__ float As[64][17];
    __shared__ float Bs[16][65];
    int n0 = blockIdx.x * 64;
    int m0 = blockIdx.y * 64;
    int tid = threadIdx.x;
    int tx = tid & 15, ty = tid >> 4;
    float acc[4][4] = {};
    for (int k0 = 0; k0 < 1024; k0 += 16) {
        #pragma unroll
        for (int i = 0; i < 4; i++) {
            int lin = tid + i*256; int r = lin >> 4, k = lin & 15;
            As[r][k] = A[(size_t)(m0 + r)*Hc + k0 + k];
        }
        #pragma unroll
        for (int i = 0; i < 4; i++) {
            int lin = tid + i*256; int r = lin >> 6, c = lin & 63;
            Bs[r][c] = wo[(size_t)(k0 + r)*Hc + n0 + c];
        }
        __syncthreads();
        #pragma unroll
        for (int kk = 0; kk < 16; kk++) {
            float a[4], b[4];
            #pragma unroll
            for (int i = 0; i < 4; i++) a[i] = As[ty*4+i][kk];
            #pragma unroll
            for (int j = 0; j < 4; j++) b[j] = Bs[kk][tx*4+j];
            #pragma unroll
            for (int i = 0; i < 4; i++)
                #pragma unroll
                for (int j = 0; j < 4; j++) acc[i][j] += a[i]*b[j];
        }
        __syncthreads();
    }
    #pragma unroll
    for (int i = 0; i < 4; i++) {
        int m = m0 + ty*4 + i;
        #pragma unroll
        for (int j = 0; j < 4; j++) {
            int n = n0 + tx*4 + j;
            out[(size_t)m*Hc + n] = acc[i][j] + resid[(size_t)m*Hc + n];
        }
    }
}

// ---------------- router: logits, softmax, top-2, counts ----------------
__global__ __launch_bounds__(256) void router_kernel(const float* __restrict__ xn2,
        const float* __restrict__ rw, int* __restrict__ counts,
        int* __restrict__ topk_e, float* __restrict__ topk_w) {
    int t = blockIdx.x, tid = threadIdx.x;
    float part[8] = {};
    for (int h = tid; h < 1024; h += 256) {
        float x = xn2[(size_t)t*Hc + h];
        #pragma unroll
        for (int e = 0; e < 8; e++) part[e] += x * rw[h*8 + e];
    }
    __shared__ float red[8][256];
    #pragma unroll
    for (int e = 0; e < 8; e++) red[e][tid] = part[e];
    __syncthreads();
    for (int s = 128; s > 0; s >>= 1) {
        if (tid < s) {
            #pragma unroll
            for (int e = 0; e < 8; e++) red[e][tid] += red[e][tid+s];
        }
        __syncthreads();
    }
    if (tid == 0) {
        float lg[8]; float mx = -1e30f;
        for (int e = 0; e < 8; e++) { lg[e] = red[e][0]; mx = fmaxf(mx, lg[e]); }
        float p[8]; float sum = 0.f;
        for (int e = 0; e < 8; e++) { p[e] = expf(lg[e]-mx); sum += p[e]; }
        for (int e = 0; e < 8; e++) p[e] /= sum;
        int e0 = 0;
        for (int e = 1; e < 8; e++) if (p[e] > p[e0]) e0 = e;
        int e1 = -1;
        for (int e = 0; e < 8; e++) { if (e == e0) continue; if (e1 < 0 || p[e] > p[e1]) e1 = e; }
        float w0 = p[e0], w1 = p[e1]; float wsum = w0 + w1; w0 /= wsum; w1 /= wsum;
        topk_e[t*2] = e0; topk_e[t*2+1] = e1;
        topk_w[t*2] = w0; topk_w[t*2+1] = w1;
        atomicAdd(&counts[e0], 1); atomicAdd(&counts[e1], 1);
    }
}

__global__ void prefix_kernel(const int* __restrict__ counts, int* __restrict__ offsets) {
    if (threadIdx.x == 0 && blockIdx.x == 0) {
        int acc = 0;
        for (int e = 0; e < 8; e++) { offsets[e] = acc; acc += counts[e]; }
    }
}

__global__ __launch_bounds__(256) void fill_kernel(const int* __restrict__ topk_e,
        const float* __restrict__ topk_w, const int* __restrict__ offsets,
        int* __restrict__ fill, int* __restrict__ list_tok, float* __restrict__ list_w) {
    int t = blockIdx.x*256 + threadIdx.x;
    if (t >= Tc) return;
    #pragma unroll
    for (int j = 0; j < 2; j++) {
        int e = topk_e[t*2+j]; float w = topk_w[t*2+j];
        int slot = atomicAdd(&fill[e], 1);
        list_tok[offsets[e]+slot] = t;
        list_w[offsets[e]+slot] = w;
    }
}

// ---------------- gathered gate/up GEMM + SiLU*up ----------------
__global__ __launch_bounds__(256) void gateup_gemm(const float* __restrict__ xn2,
        const float* __restrict__ wg, const float* __restrict__ wu,
        const int* __restrict__ counts, const int* __restrict__ offsets,
        const int* __restrict__ list_tok, float* __restrict__ act) {
    int e = blockIdx.z;
    int cnt = counts[e];
    int m0 = blockIdx.y * 64;
    if (m0 >= cnt) return;
    int n0 = blockIdx.x * 64;
    int aoff = offsets[e];
    __shared__ float As[64][17];
    __shared__ float Bg[16][65];
    __shared__ float Bu[16][65];
    __shared__ int tok[64];
    int tid = threadIdx.x;
    if (tid < 64) tok[tid] = list_tok[aoff + min(m0 + tid, cnt-1)];
    __syncthreads();
    int tx = tid & 15, ty = tid >> 4;
    const float* wge = wg + (size_t)e*Hc*Ic;
    const float* wue = wu + (size_t)e*Hc*Ic;
    float accg[4][4] = {}, accu[4][4] = {};
    for (int k0 = 0; k0 < 1024; k0 += 16) {
        #pragma unroll
        for (int i = 0; i < 4; i++) {
            int lin = tid + i*256; int r = lin >> 4, k = lin & 15;
            As[r][k] = xn2[(size_t)tok[r]*Hc + k0 + k];
        }
        #pragma unroll
        for (int i = 0; i < 4; i++) {
            int lin = tid + i*256; int r = lin >> 6, c = lin & 63;
            Bg[r][c] = wge[(size_t)(k0+r)*Ic + n0 + c];
            Bu[r][c] = wue[(size_t)(k0+r)*Ic + n0 + c];
        }
        __syncthreads();
        #pragma unroll
        for (int kk = 0; kk < 16; kk++) {
            float a[4], bg[4], bu[4];
            #pragma unroll
            for (int i = 0; i < 4; i++) a[i] = As[ty*4+i][kk];
            #pragma unroll
            for (int j = 0; j < 4; j++) { bg[j] = Bg[kk][tx*4+j]; bu[j] = Bu[kk][tx*4+j]; }
            #pragma unroll
            for (int i = 0; i < 4; i++)
                #pragma unroll
                for (int j = 0; j < 4; j++) { accg[i][j] += a[i]*bg[j]; accu[i][j] += a[i]*bu[j]; }
        }
        __syncthreads();
    }
    #pragma unroll
    for (int i = 0; i < 4; i++) {
        int r = m0 + ty*4 + i;
        if (r >= cnt) break;
        #pragma unroll
        for (int j = 0; j < 4; j++) {
            int n = n0 + tx*4 + j;
            float g = accg[i][j], u = accu[i][j];
            float sg = g / (1.f + expf(-g));
            act[(size_t)(aoff + r)*Ic + n] = sg * u;
        }
    }
}

// ---------------- down GEMM + weighted atomic scatter ----------------
__global__ __launch_bounds__(256) void down_gemm(const float* __restrict__ act,
        const float* __restrict__ wd, const int* __restrict__ counts,
        const int* __restrict__ offsets, const int* __restrict__ list_tok,
        const float* __restrict__ list_w, float* __restrict__ out) {
    int e = blockIdx.z;
    int cnt = counts[e];
    int m0 = blockIdx.y * 64;
    if (m0 >= cnt) return;
    int n0 = blockIdx.x * 64;
    int aoff = offsets[e];
    __shared__ float As[64][17];
    __shared__ float Bs[16][65];
    int tid = threadIdx.x;
    int tx = tid & 15, ty = tid >> 4;
    const float* wde = wd + (size_t)e*Ic*Hc;
    float acc[4][4] = {};
    for (int k0 = 0; k0 < Ic; k0 += 16) {
        #pragma unroll
        for (int i = 0; i < 4; i++) {
            int lin = tid + i*256; int r = lin >> 4, k = lin & 15;
            int rr = min(m0 + r, cnt-1);
            As[r][k] = act[(size_t)(aoff + rr)*Ic + k0 + k];
        }
        #pragma unroll
        for (int i = 0; i < 4; i++) {
            int lin = tid + i*256; int r = lin >> 6, c = lin & 63;
            Bs[r][c] = wde[(size_t)(k0+r)*Hc + n0 + c];
        }
        __syncthreads();
        #pragma unroll
        for (int kk = 0; kk < 16; kk++) {
            float a[4], b[4];
            #pragma unroll
            for (int i = 0; i < 4; i++) a[i] = As[ty*4+i][kk];
            #pragma unroll
            for (int j = 0; j < 4; j++) b[j] = Bs[kk][tx*4+j];
            #pragma unroll
            for (int i = 0; i < 4; i++)
                #pragma unroll
                for (int j = 0; j < 4; j++) acc[i][j] += a[i]*b[j];
        }
        __syncthreads();
    }
    #pragma unroll
    for (int i = 0; i < 4; i++) {
        int r = m0 + ty*4 + i;
        if (r >= cnt) break;
        int t = list_tok[aoff + r];
        float w = list_w[aoff + r];
        #pragma unroll
        for (int j = 0; j < 4; j++) {
            int n = n0 + tx*4 + j;
            atomicAdd(&out[(size_t)t*Hc + n], w*acc[i][j]);
        }
    }
}

// ---------------- launch ----------------
extern "C" void kernel_launch(void* const* d_in, const int* in_sizes, int n_in,
                              void* d_out, int out_size, void* d_ws, size_t ws_size,
                              hipStream_t stream) {
    const float* hidden = (const float*)d_in[0];
    // d_in[1] = position_ids (int64) — positions are arange(S); use s index directly.
    const float* ln1 = (const float*)d_in[2];
    const float* ln2 = (const float*)d_in[3];
    const float* wq  = (const float*)d_in[4];
    const float* wk  = (const float*)d_in[5];
    const float* wv  = (const float*)d_in[6];
    const float* wo  = (const float*)d_in[7];
    const float* rw  = (const float*)d_in[8];
    const float* wg  = (const float*)d_in[9];
    const float* wu  = (const float*)d_in[10];
    const float* wd  = (const float*)d_in[11];
    float* out = (float*)d_out;
    float* ws  = (float*)d_ws;

    float* xn1  = ws + OFF_XN1;
    float* qb   = ws + OFF_Q;
    float* kb   = ws + OFF_K;
    float* vb   = ws + OFF_V;
    float* attn = ws + OFF_ATT;
    float* xn2  = ws + OFF_XN2;
    float* act  = ws + OFF_ACT;
    int*   route    = (int*)(ws + OFF_ROUTE);
    int*   counts   = route;          // 8
    int*   fillc    = route + 8;      // 8
    int*   offsets  = route + 16;     // 8
    int*   topk_e   = route + 24;             // 2T
    float* topk_w   = (float*)(route + 24 + 2*Tc);  // 2T
    int*   list_tok = route + 24 + 4*Tc;            // 2T
    float* list_w   = (float*)(route + 24 + 6*Tc);  // 2T

    // zero counts + fill (16 ints)
    hipMemsetAsync(counts, 0, 16*sizeof(int), stream);

    rmsnorm_kernel<<<Tc, 256, 0, stream>>>(hidden, ln1, xn1);
    qkv_gemm<<<dim3(24, 32), 256, 0, stream>>>(xn1, wq, wk, wv, qb, kb, vb);
    rope_kernel<<<(Tc*(NHc+NKVc)*32 + 255)/256, 256, 0, stream>>>(qb, kb);
    attn_kernel<<<dim3(16, 16, 2), 256, 0, stream>>>(qb, kb, vb, attn);
    wo_gemm<<<dim3(16, 32), 256, 0, stream>>>(attn, wo, hidden, out);
    rmsnorm_kernel<<<Tc, 256, 0, stream>>>(out, ln2, xn2);
    router_kernel<<<Tc, 256, 0, stream>>>(xn2, rw, counts, topk_e, topk_w);
    prefix_kernel<<<1, 64, 0, stream>>>(counts, offsets);
    fill_kernel<<<(Tc+255)/256, 256, 0, stream>>>(topk_e, topk_w, offsets, fillc, list_tok, list_w);
    gateup_gemm<<<dim3(Ic/64, Tc/64, Ec), 256, 0, stream>>>(xn2, wg, wu, counts, offsets, list_tok, act);
    down_gemm<<<dim3(Hc/64, Tc/64, Ec), 256, 0, stream>>>(act, wd, counts, offsets, list_tok, list_w, out);
}

// Round 3
// 1243.857 us; speedup vs baseline: 2.0649x; 2.0649x over previous
//
#include <hip/hip_runtime.h>
#include <hip/hip_bf16.h>
#include <math.h>

#define Bc 2
#define Sc 1024
#define Hc 1024
#define NHc 16
#define NKVc 4
#define HDc 64
#define Ec 8
#define TOPKc 2
#define Ic 3584
#define Tc (Bc*Sc)
#define EPSc 1e-5f

typedef __attribute__((ext_vector_type(8))) short bf16x8;
typedef __attribute__((ext_vector_type(4))) float f32x4;

__device__ __forceinline__ unsigned short f2bf(float f) {
    union { float f; unsigned u; } v; v.f = f;
    unsigned r = v.u + 0x7fffu + ((v.u >> 16) & 1u);
    return (unsigned short)(r >> 16);
}

// ---------------- ws layout (bytes) ----------------
// Pre-router path is fp32 (router top-2 selection is discontinuous in hidden;
// bf16 errors flip expert choices -> O(1) output errors). MoE is bf16 MFMA.
static const size_t OFF_XN1  = 0;                          // fp32 T*H (8MB); reused as attn out
static const size_t OFF_QB   = 8*1024*1024;                // fp32 (8MB)
static const size_t OFF_KB   = OFF_QB + 8*1024*1024;       // fp32 (2MB)
static const size_t OFF_VB   = OFF_KB + 2*1024*1024;       // fp32 (2MB)
static const size_t OFF_XN2F = OFF_VB + 2*1024*1024;       // fp32 T*H (8MB)
static const size_t OFF_XN2B = OFF_XN2F + 8*1024*1024;     // bf16 T*H (4MB)
static const size_t OFF_ACT  = OFF_XN2B + 4*1024*1024;     // bf16 4096*3584 (28MB)
static const size_t OFF_ROUTE= OFF_ACT + (size_t)4096*3584*2;

// ---------------- rmsnorm (fp32 in, fp32 out + optional bf16 out) ----------------
__global__ __launch_bounds__(256) void rmsnorm_kernel(const float* __restrict__ x,
        const float* __restrict__ w, float* __restrict__ outf,
        unsigned short* __restrict__ outb) {
    int t = blockIdx.x;
    int tid = threadIdx.x;
    const float* row = x + (size_t)t * Hc;
    float ss = 0.f;
    for (int h = tid; h < Hc; h += 256) { float v = row[h]; ss += v*v; }
    __shared__ float red[256];
    red[tid] = ss; __syncthreads();
    for (int s = 128; s > 0; s >>= 1) { if (tid < s) red[tid] += red[tid+s]; __syncthreads(); }
    float scale = rsqrtf(red[0] / (float)Hc + EPSc);
    for (int h = tid; h < Hc; h += 256) {
        float v = row[h] * scale * w[h];
        outf[(size_t)t*Hc + h] = v;
        if (outb) outb[(size_t)t*Hc + h] = f2bf(v);
    }
}

// ---------------- fused QKV GEMM fp32 (round-1, verified) ----------------
__global__ __launch_bounds__(256) void qkv_gemm(const float* __restrict__ A,
        const float* __restrict__ wq, const float* __restrict__ wk, const float* __restrict__ wv,
        float* __restrict__ qout, float* __restrict__ kout, float* __restrict__ vout) {
    __shared__ float As[64][17];
    __shared__ float Bs[16][65];
    int n0 = blockIdx.x * 64;
    int m0 = blockIdx.y * 64;
    int tid = threadIdx.x;
    int tx = tid & 15, ty = tid >> 4;
    const float* Bp; int ldb, c0;
    if (n0 < 1024)      { Bp = wq; ldb = 1024; c0 = n0; }
    else if (n0 < 1280) { Bp = wk; ldb = 256;  c0 = n0 - 1024; }
    else                { Bp = wv; ldb = 256;  c0 = n0 - 1280; }
    float acc[4][4] = {};
    for (int k0 = 0; k0 < 1024; k0 += 16) {
        #pragma unroll
        for (int i = 0; i < 4; i++) {
            int lin = tid + i*256; int r = lin >> 4, k = lin & 15;
            As[r][k] = A[(size_t)(m0 + r)*Hc + k0 + k];
        }
        #pragma unroll
        for (int i = 0; i < 4; i++) {
            int lin = tid + i*256; int r = lin >> 6, c = lin & 63;
            Bs[r][c] = Bp[(size_t)(k0 + r)*ldb + c0 + c];
        }
        __syncthreads();
        #pragma unroll
        for (int kk = 0; kk < 16; kk++) {
            float a[4], b[4];
            #pragma unroll
            for (int i = 0; i < 4; i++) a[i] = As[ty*4+i][kk];
            #pragma unroll
            for (int j = 0; j < 4; j++) b[j] = Bs[kk][tx*4+j];
            #pragma unroll
            for (int i = 0; i < 4; i++)
                #pragma unroll
                for (int j = 0; j < 4; j++) acc[i][j] += a[i]*b[j];
        }
        __syncthreads();
    }
    #pragma unroll
    for (int i = 0; i < 4; i++) {
        int m = m0 + ty*4 + i;
        #pragma unroll
        for (int j = 0; j < 4; j++) {
            int n = n0 + tx*4 + j;
            float val = acc[i][j];
            if (n < 1024)      qout[(size_t)m*1024 + n] = val;
            else if (n < 1280) kout[(size_t)m*256 + (n-1024)] = val;
            else               vout[(size_t)m*256 + (n-1280)] = val;
        }
    }
}

// ---------------- RoPE ----------------
__global__ __launch_bounds__(256) void rope_kernel(float* __restrict__ q, float* __restrict__ k) {
    int idx = blockIdx.x*256 + threadIdx.x;
    const int total = Tc*(NHc+NKVc)*32;
    if (idx >= total) return;
    int d = idx & 31;
    int rest = idx >> 5;
    int head = rest % (NHc+NKVc);
    int t = rest / (NHc+NKVc);
    int s = t & (Sc-1);
    float inv = powf(1.0e6f, -(float)d / 32.0f);
    float ang = (float)s * inv;
    float c = cosf(ang), sn = sinf(ang);
    float* base;
    if (head < NHc) base = q + (size_t)t*1024 + head*64;
    else            base = k + (size_t)t*256  + (head-NHc)*64;
    float x1 = base[d], x2 = base[d+32];
    base[d]    = x1*c - x2*sn;
    base[d+32] = x2*c + x1*sn;
}

// ---------------- flash attention fp32 (round-1, verified) ----------------
__global__ __launch_bounds__(256) void attn_kernel(const float* __restrict__ q,
        const float* __restrict__ kbuf, const float* __restrict__ vbuf,
        float* __restrict__ attn) {
    __shared__ float Qs[64][65];
    __shared__ float KVs[64][65];
    __shared__ float Ps[64][65];
    __shared__ float m_s[64], l_s[64], al_s[64];
    int q0 = blockIdx.x * 64;
    int h  = blockIdx.y;
    int b  = blockIdx.z;
    int hk = h >> 2;
    int tid = threadIdx.x;
    int tx = tid & 15, ty = tid >> 4;
    #pragma unroll
    for (int i = 0; i < 16; i++) {
        int lin = tid + i*256; int r = lin >> 6, d = lin & 63;
        Qs[r][d] = q[((size_t)(b*Sc + q0 + r))*1024 + h*64 + d];
    }
    if (tid < 64) { m_s[tid] = -INFINITY; l_s[tid] = 0.f; }
    float O[4][4] = {};
    for (int j0 = 0; j0 <= q0; j0 += 64) {
        __syncthreads();
        #pragma unroll
        for (int i = 0; i < 16; i++) {
            int lin = tid + i*256; int r = lin >> 6, d = lin & 63;
            KVs[r][d] = kbuf[((size_t)(b*Sc + j0 + r))*256 + hk*64 + d];
        }
        __syncthreads();
        float sc[4][4] = {};
        for (int d = 0; d < 64; d++) {
            float a[4], bb[4];
            #pragma unroll
            for (int i = 0; i < 4; i++) a[i] = Qs[ty*4+i][d];
            #pragma unroll
            for (int j = 0; j < 4; j++) bb[j] = KVs[tx*4+j][d];
            #pragma unroll
            for (int i = 0; i < 4; i++)
                #pragma unroll
                for (int j = 0; j < 4; j++) sc[i][j] += a[i]*bb[j];
        }
        bool diag = (j0 == q0);
        #pragma unroll
        for (int i = 0; i < 4; i++) {
            int r = ty*4+i;
            #pragma unroll
            for (int j = 0; j < 4; j++) {
                int c = tx*4+j;
                float v = sc[i][j]*0.125f;
                if (diag && c > r) v = -1e30f;
                Ps[r][c] = v;
            }
        }
        __syncthreads();
        if (tid < 64) {
            int r = tid;
            float mx = -1e30f;
            for (int c = 0; c < 64; c++) mx = fmaxf(mx, Ps[r][c]);
            float newm = fmaxf(m_s[r], mx);
            float alpha = expf(m_s[r] - newm);
            float sum = 0.f;
            for (int c = 0; c < 64; c++) { float p = expf(Ps[r][c] - newm); Ps[r][c] = p; sum += p; }
            l_s[r] = l_s[r]*alpha + sum;
            m_s[r] = newm;
            al_s[r] = alpha;
        }
        #pragma unroll
        for (int i = 0; i < 16; i++) {
            int lin = tid + i*256; int r = lin >> 6, d = lin & 63;
            KVs[r][d] = vbuf[((size_t)(b*Sc + j0 + r))*256 + hk*64 + d];
        }
        __syncthreads();
        #pragma unroll
        for (int i = 0; i < 4; i++) {
            float al = al_s[ty*4+i];
            #pragma unroll
            for (int j = 0; j < 4; j++) O[i][j] *= al;
        }
        for (int c = 0; c < 64; c++) {
            float p[4], vv[4];
            #pragma unroll
            for (int i = 0; i < 4; i++) p[i] = Ps[ty*4+i][c];
            #pragma unroll
            for (int j = 0; j < 4; j++) vv[j] = KVs[c][tx*4+j];
            #pragma unroll
            for (int i = 0; i < 4; i++)
                #pragma unroll
                for (int j = 0; j < 4; j++) O[i][j] += p[i]*vv[j];
        }
    }
    #pragma unroll
    for (int i = 0; i < 4; i++) {
        int r = ty*4+i;
        float inv_l = 1.f / l_s[r];
        int m = b*Sc + q0 + r;
        #pragma unroll
        for (int j = 0; j < 4; j++) {
            int d = tx*4+j;
            attn[(size_t)m*1024 + h*64 + d] = O[i][j]*inv_l;
        }
    }
}

// ---------------- WO GEMM + residual fp32 (round-1, verified) ----------------
__global__ __launch_bounds__(256) void wo_gemm(const float* __restrict__ A,
        const float* __restrict__ wo, const float* __restrict__ resid,
        float* __restrict__ out) {
    __shared__ float As[64][17];
    __shared__ float Bs[16][65];
    int n0 = blockIdx.x * 64;
    int m0 = blockIdx.y * 64;
    int tid = threadIdx.x;
    int tx = tid & 15, ty = tid >> 4;
    float acc[4][4] = {};
    for (int k0 = 0; k0 < 1024; k0 += 16) {
        #pragma unroll
        for (int i = 0; i < 4; i++) {
            int lin = tid + i*256; int r = lin >> 4, k = lin & 15;
            As[r][k] = A[(size_t)(m0 + r)*Hc + k0 + k];
        }
        #pragma unroll
        for (int i = 0; i < 4; i++) {
            int lin = tid + i*256; int r = lin >> 6, c = lin & 63;
            Bs[r][c] = wo[(size_t)(k0 + r)*Hc + n0 + c];
        }
        __syncthreads();
        #pragma unroll
        for (int kk = 0; kk < 16; kk++) {
            float a[4], b[4];
            #pragma unroll
            for (int i = 0; i < 4; i++) a[i] = As[ty*4+i][kk];
            #pragma unroll
            for (int j = 0; j < 4; j++) b[j] = Bs[kk][tx*4+j];
            #pragma unroll
            for (int i = 0; i < 4; i++)
                #pragma unroll
                for (int j = 0; j < 4; j++) acc[i][j] += a[i]*b[j];
        }
        __syncthreads();
    }
    #pragma unroll
    for (int i = 0; i < 4; i++) {
        int m = m0 + ty*4 + i;
        #pragma unroll
        for (int j = 0; j < 4; j++) {
            int n = n0 + tx*4 + j;
            out[(size_t)m*Hc + n] = acc[i][j] + resid[(size_t)m*Hc + n];
        }
    }
}

// ---------------- router (fp32) ----------------
__global__ __launch_bounds__(256) void router_kernel(const float* __restrict__ xn2,
        const float* __restrict__ rw, int* __restrict__ counts,
        int* __restrict__ topk_e, float* __restrict__ topk_w) {
    int t = blockIdx.x, tid = threadIdx.x;
    float part[8] = {};
    for (int h = tid; h < 1024; h += 256) {
        float x = xn2[(size_t)t*Hc + h];
        #pragma unroll
        for (int e = 0; e < 8; e++) part[e] += x * rw[h*8 + e];
    }
    __shared__ float red[8][256];
    #pragma unroll
    for (int e = 0; e < 8; e++) red[e][tid] = part[e];
    __syncthreads();
    for (int s = 128; s > 0; s >>= 1) {
        if (tid < s) {
            #pragma unroll
            for (int e = 0; e < 8; e++) red[e][tid] += red[e][tid+s];
        }
        __syncthreads();
    }
    if (tid == 0) {
        float lg[8]; float mx = -1e30f;
        for (int e = 0; e < 8; e++) { lg[e] = red[e][0]; mx = fmaxf(mx, lg[e]); }
        float p[8]; float sum = 0.f;
        for (int e = 0; e < 8; e++) { p[e] = expf(lg[e]-mx); sum += p[e]; }
        for (int e = 0; e < 8; e++) p[e] /= sum;
        int e0 = 0;
        for (int e = 1; e < 8; e++) if (p[e] > p[e0]) e0 = e;
        int e1 = -1;
        for (int e = 0; e < 8; e++) { if (e == e0) continue; if (e1 < 0 || p[e] > p[e1]) e1 = e; }
        float w0 = p[e0], w1 = p[e1]; float wsum = w0 + w1; w0 /= wsum; w1 /= wsum;
        topk_e[t*2] = e0; topk_e[t*2+1] = e1;
        topk_w[t*2] = w0; topk_w[t*2+1] = w1;
        atomicAdd(&counts[e0], 1); atomicAdd(&counts[e1], 1);
    }
}

__global__ void prefix_kernel(const int* __restrict__ counts, int* __restrict__ offsets) {
    if (threadIdx.x == 0 && blockIdx.x == 0) {
        int acc = 0;
        for (int e = 0; e < 8; e++) { offsets[e] = acc; acc += counts[e]; }
    }
}

__global__ __launch_bounds__(256) void fill_kernel(const int* __restrict__ topk_e,
        const float* __restrict__ topk_w, const int* __restrict__ offsets,
        int* __restrict__ fill, int* __restrict__ list_tok, float* __restrict__ list_w) {
    int t = blockIdx.x*256 + threadIdx.x;
    if (t >= Tc) return;
    #pragma unroll
    for (int j = 0; j < 2; j++) {
        int e = topk_e[t*2+j]; float w = topk_w[t*2+j];
        int slot = atomicAdd(&fill[e], 1);
        list_tok[offsets[e]+slot] = t;
        list_w[offsets[e]+slot] = w;
    }
}

// ---------------- gate+up fused bf16 MFMA GEMM: BM=64, BN=128, silu epilogue ----------------
__global__ __launch_bounds__(256) void gemm_gateup(const unsigned short* __restrict__ xn2b,
        const float* __restrict__ wg, const float* __restrict__ wu,
        const int* __restrict__ counts, const int* __restrict__ offsets,
        const int* __restrict__ list_tok, unsigned short* __restrict__ act) {
    int e = blockIdx.z;
    int cnt = counts[e];
    int m0 = blockIdx.y * 64;
    if (m0 >= cnt) return;
    int n0 = blockIdx.x * 128;
    int aoff = offsets[e];
    __shared__ unsigned short As[64*40];
    __shared__ unsigned short Bg[128*40];
    __shared__ unsigned short Bu[128*40];
    __shared__ int toks[64];
    int tid = threadIdx.x;
    if (tid < 64) toks[tid] = list_tok[aoff + min(m0 + tid, cnt-1)];
    __syncthreads();
    const float* Bgp = wg + (size_t)e*Hc*Ic + n0;
    const float* Bup = wu + (size_t)e*Hc*Ic + n0;
    int lane = tid & 63, wave = tid >> 6;
    int wm = wave >> 1, wn = wave & 1;
    int ml = lane & 15, quad = lane >> 4;
    f32x4 accg[2][4] = {}, accu[2][4] = {};
    for (int k0 = 0; k0 < Hc; k0 += 32) {
        {
            int r = tid >> 2, part = tid & 3;
            uint4 v = *reinterpret_cast<const uint4*>(xn2b + (size_t)toks[r]*Hc + k0 + part*8);
            *reinterpret_cast<uint4*>(&As[r*40 + part*8]) = v;
        }
        #pragma unroll
        for (int it = 0; it < 8; it++) {
            int lin = tid + it*256;
            int n = lin & 127, kp = lin >> 7;
            float g0 = Bgp[(size_t)(k0 + 2*kp)*Ic + n];
            float g1 = Bgp[(size_t)(k0 + 2*kp + 1)*Ic + n];
            float u0 = Bup[(size_t)(k0 + 2*kp)*Ic + n];
            float u1 = Bup[(size_t)(k0 + 2*kp + 1)*Ic + n];
            *reinterpret_cast<unsigned*>(&Bg[n*40 + 2*kp]) = (unsigned)f2bf(g0) | ((unsigned)f2bf(g1) << 16);
            *reinterpret_cast<unsigned*>(&Bu[n*40 + 2*kp]) = (unsigned)f2bf(u0) | ((unsigned)f2bf(u1) << 16);
        }
        __syncthreads();
        bf16x8 a[2], bg[4], bu[4];
        #pragma unroll
        for (int mt = 0; mt < 2; mt++)
            a[mt] = *reinterpret_cast<const bf16x8*>(&As[(wm*32 + mt*16 + ml)*40 + quad*8]);
        #pragma unroll
        for (int nt = 0; nt < 4; nt++) {
            bg[nt] = *reinterpret_cast<const bf16x8*>(&Bg[(wn*64 + nt*16 + ml)*40 + quad*8]);
            bu[nt] = *reinterpret_cast<const bf16x8*>(&Bu[(wn*64 + nt*16 + ml)*40 + quad*8]);
        }
        #pragma unroll
        for (int mt = 0; mt < 2; mt++)
            #pragma unroll
            for (int nt = 0; nt < 4; nt++) {
                accg[mt][nt] = __builtin_amdgcn_mfma_f32_16x16x32_bf16(a[mt], bg[nt], accg[mt][nt], 0, 0, 0);
                accu[mt][nt] = __builtin_amdgcn_mfma_f32_16x16x32_bf16(a[mt], bu[nt], accu[mt][nt], 0, 0, 0);
            }
        __syncthreads();
    }
    #pragma unroll
    for (int mt = 0; mt < 2; mt++)
        #pragma unroll
        for (int nt = 0; nt < 4; nt++)
            #pragma unroll
            for (int rg = 0; rg < 4; rg++) {
                int rowl = wm*32 + mt*16 + quad*4 + rg;
                if (m0 + rowl < cnt) {
                    int n = n0 + wn*64 + nt*16 + ml;
                    float g = accg[mt][nt][rg], u = accu[mt][nt][rg];
                    float sg = g / (1.f + expf(-g));
                    act[(size_t)(aoff + m0 + rowl)*Ic + n] = f2bf(sg * u);
                }
            }
}

// ---------------- down bf16 MFMA GEMM (128x128) + weighted atomic scatter ----------------
__global__ __launch_bounds__(256) void gemm_down(const unsigned short* __restrict__ act,
        const float* __restrict__ wd, const int* __restrict__ counts,
        const int* __restrict__ offsets, const int* __restrict__ list_tok,
        const float* __restrict__ list_w, float* __restrict__ out) {
    int e = blockIdx.z;
    int cnt = counts[e];
    int m0 = blockIdx.y * 128;
    if (m0 >= cnt) return;
    int n0 = blockIdx.x * 128;
    int aoff = offsets[e];
    __shared__ unsigned short As[128*40];
    __shared__ unsigned short Bs[128*40];
    const unsigned short* A = act + (size_t)(aoff + m0)*Ic;
    const float* B = wd + (size_t)e*Ic*Hc + n0;
    int rowclamp = cnt - 1 - m0;
    int tid = threadIdx.x;
    int lane = tid & 63, wave = tid >> 6;
    int wm = wave >> 1, wn = wave & 1;
    int ml = lane & 15, quad = lane >> 4;
    f32x4 acc[4][4] = {};
    for (int k0 = 0; k0 < Ic; k0 += 32) {
        #pragma unroll
        for (int it = 0; it < 2; it++) {
            int lin = tid + it*256;
            int r = lin >> 2, part = lin & 3;
            int rc = min(r, rowclamp);
            uint4 v = *reinterpret_cast<const uint4*>(A + (size_t)rc*Ic + k0 + part*8);
            *reinterpret_cast<uint4*>(&As[r*40 + part*8]) = v;
        }
        #pragma unroll
        for (int it = 0; it < 8; it++) {
            int lin = tid + it*256;
            int n = lin & 127, kp = lin >> 7;
            float b0 = B[(size_t)(k0 + 2*kp)*Hc + n];
            float b1 = B[(size_t)(k0 + 2*kp + 1)*Hc + n];
            *reinterpret_cast<unsigned*>(&Bs[n*40 + 2*kp]) = (unsigned)f2bf(b0) | ((unsigned)f2bf(b1) << 16);
        }
        __syncthreads();
        bf16x8 a[4], b[4];
        #pragma unroll
        for (int mt = 0; mt < 4; mt++)
            a[mt] = *reinterpret_cast<const bf16x8*>(&As[(wm*64 + mt*16 + ml)*40 + quad*8]);
        #pragma unroll
        for (int nt = 0; nt < 4; nt++)
            b[nt] = *reinterpret_cast<const bf16x8*>(&Bs[(wn*64 + nt*16 + ml)*40 + quad*8]);
        #pragma unroll
        for (int mt = 0; mt < 4; mt++)
            #pragma unroll
            for (int nt = 0; nt < 4; nt++)
                acc[mt][nt] = __builtin_amdgcn_mfma_f32_16x16x32_bf16(a[mt], b[nt], acc[mt][nt], 0, 0, 0);
        __syncthreads();
    }
    #pragma unroll
    for (int mt = 0; mt < 4; mt++)
        #pragma unroll
        for (int nt = 0; nt < 4; nt++)
            #pragma unroll
            for (int rg = 0; rg < 4; rg++) {
                int rowl = wm*64 + mt*16 + quad*4 + rg;
                if (m0 + rowl < cnt) {
                    int t = list_tok[aoff + m0 + rowl];
                    float w = list_w[aoff + m0 + rowl];
                    int n = n0 + wn*64 + nt*16 + ml;
                    atomicAdd(&out[(size_t)t*Hc + n], w * acc[mt][nt][rg]);
                }
            }
}

// ---------------- launch ----------------
extern "C" void kernel_launch(void* const* d_in, const int* in_sizes, int n_in,
                              void* d_out, int out_size, void* d_ws, size_t ws_size,
                              hipStream_t stream) {
    const float* hidden = (const float*)d_in[0];
    const float* ln1 = (const float*)d_in[2];
    const float* ln2 = (const float*)d_in[3];
    const float* wq  = (const float*)d_in[4];
    const float* wk  = (const float*)d_in[5];
    const float* wv  = (const float*)d_in[6];
    const float* wo  = (const float*)d_in[7];
    const float* rw  = (const float*)d_in[8];
    const float* wg  = (const float*)d_in[9];
    const float* wu  = (const float*)d_in[10];
    const float* wd  = (const float*)d_in[11];
    float* out = (float*)d_out;
    char* ws = (char*)d_ws;

    float* xn1f  = (float*)(ws + OFF_XN1);
    float* attnf = xn1f;   // reuse after qkv
    float* qb    = (float*)(ws + OFF_QB);
    float* kb    = (float*)(ws + OFF_KB);
    float* vb    = (float*)(ws + OFF_VB);
    float* xn2f  = (float*)(ws + OFF_XN2F);
    unsigned short* xn2b = (unsigned short*)(ws + OFF_XN2B);
    unsigned short* act  = (unsigned short*)(ws + OFF_ACT);
    int*   route    = (int*)(ws + OFF_ROUTE);
    int*   counts   = route;
    int*   fillc    = route + 8;
    int*   offsets  = route + 16;
    int*   topk_e   = route + 24;
    float* topk_w   = (float*)(route + 24 + 2*Tc);
    int*   list_tok = route + 24 + 4*Tc;
    float* list_w   = (float*)(route + 24 + 6*Tc);

    hipMemsetAsync(counts, 0, 16*sizeof(int), stream);

    rmsnorm_kernel<<<Tc, 256, 0, stream>>>(hidden, ln1, xn1f, nullptr);
    qkv_gemm<<<dim3(24, 32), 256, 0, stream>>>(xn1f, wq, wk, wv, qb, kb, vb);
    rope_kernel<<<(Tc*(NHc+NKVc)*32 + 255)/256, 256, 0, stream>>>(qb, kb);
    attn_kernel<<<dim3(16, 16, 2), 256, 0, stream>>>(qb, kb, vb, attnf);
    wo_gemm<<<dim3(16, 32), 256, 0, stream>>>(attnf, wo, hidden, out);
    rmsnorm_kernel<<<Tc, 256, 0, stream>>>(out, ln2, xn2f, xn2b);
    router_kernel<<<Tc, 256, 0, stream>>>(xn2f, rw, counts, topk_e, topk_w);
    prefix_kernel<<<1, 64, 0, stream>>>(counts, offsets);
    fill_kernel<<<(Tc+255)/256, 256, 0, stream>>>(topk_e, topk_w, offsets, fillc, list_tok, list_w);
    gemm_gateup<<<dim3(28, 64, 8), 256, 0, stream>>>(xn2b, wg, wu, counts, offsets, list_tok, act);
    gemm_down<<<dim3(8, 32, 8), 256, 0, stream>>>(act, wd, counts, offsets, list_tok, list_w, out);
}